// Round 13
// baseline (359.943 us; speedup 1.0000x reference)
//
#include <hip/hip_runtime.h>
#include <hip/hip_fp16.h>
#include <cmath>

#define N_Q 4096
#define HEADS 8
#define HEAD_DIM 24
#define HIDDEN 192

__device__ __forceinline__ float4 ld4(const float* p) { return *(const float4*)p; }

// accumulate u[0..7] += w * fp16x8 at p (16B aligned)
__device__ __forceinline__ void fma8h(float* u, float w, const __half* p) {
    uint4 raw = *(const uint4*)p;
    const __half2* h2 = reinterpret_cast<const __half2*>(&raw);
#pragma unroll
    for (int k = 0; k < 4; k++) {
        float2 f = __half22float2(h2[k]);
        u[2 * k]     = fmaf(w, f.x, u[2 * k]);
        u[2 * k + 1] = fmaf(w, f.y, u[2 * k + 1]);
    }
}

// acc[0..23] += w * fp16x24 at p (16B-aligned: offsets are 48B multiples)
__device__ __forceinline__ void corner24(float* acc, float w, const __half* p) {
    fma8h(acc,      w, p);
    fma8h(acc + 8,  w, p + 8);
    fma8h(acc + 16, w, p + 16);
}

// ---------------- prep1: transpose + wcomb (low-VGPR, high occupancy) ----------------

// [32, 262144] f32 -> [262144, 32] fp16, 256-pos tile
__device__ __forceinline__ void transpose_body(char* smem, const float* __restrict__ src,
                                               __half* __restrict__ dst, int bx, int tid)
{
    float (*lds)[33] = (float(*)[33])smem;
    const int Nv = 262144;
    int pos0 = bx * 256;
    for (int k = tid; k < 256 * 32; k += 256) {
        int c = k >> 8, p = k & 255;
        lds[p][c] = src[(size_t)c * Nv + pos0 + p];
    }
    __syncthreads();
    for (int k = tid; k < 256 * 32; k += 256) {
        int p = k >> 5, c = k & 31;
        dst[(size_t)(pos0 + p) * 32 + c] = __float2half(lds[p][c]);
    }
}

// Wcomb (512x128) = concat(Woff,Wwt) @ Wq ; biasc = concat(boff,bwt)
__device__ __forceinline__ void wcomb_body(int bx, int tid,
                                           const float* __restrict__ Woff,
                                           const float* __restrict__ Wwt,
                                           const float* __restrict__ Wq,
                                           const float* __restrict__ boff,
                                           const float* __restrict__ bwt,
                                           float* __restrict__ Wcomb,
                                           float* __restrict__ biasc)
{
    int o = bx * 2 + (tid >> 7);
    int c = tid & 127;
    const float* A = (o < 384) ? (Woff + (size_t)o * 192) : (Wwt + (size_t)(o - 384) * 192);
    float s = 0.f;
#pragma unroll 4
    for (int k = 0; k < 192; k++) s = fmaf(A[k], Wq[k * 128 + c], s);
    Wcomb[(size_t)o * 128 + c] = s;
    if (c == 0) biasc[o] = (o < 384) ? boff[o] : bwt[o - 384];
}

// ids [0,1024): transpose | [1024,1280): wcomb
__global__ __launch_bounds__(256)
void prep1_kernel(const float* __restrict__ v0, __half* __restrict__ v0T,
                  const float* __restrict__ Woff, const float* __restrict__ Wwt,
                  const float* __restrict__ Wq, const float* __restrict__ boff,
                  const float* __restrict__ bwt, float* __restrict__ Wcomb,
                  float* __restrict__ biasc)
{
    __shared__ __align__(16) char smem[33792];
    int id = blockIdx.x;
    int tid = threadIdx.x;
    if (id < 1024) {
        transpose_body(smem, v0, v0T, id, tid);
    } else {
        wcomb_body(id - 1024, tid, Woff, Wwt, Wq, boff, bwt, Wcomb, biasc);
    }
}

// ---------------- valconv (high-VGPR, compute-bound, own kernel) ----------------

// LDS-staged value conv: block = 256 positions x 48 outputs (2 heads).
// v chunk [16][256] (16KB) + W chunk [48][16] (3KB) staged per iteration.
// Output head-major valT[h][pos][24] fp16 via direct lane-contiguous stores.
template<int C>
__device__ __forceinline__ void valconv_body(char* smem, const float* __restrict__ Wv,
                                             const float* __restrict__ v,
                                             __half* __restrict__ valT, int Nv,
                                             int bx, int by, int tid)
{
    float (*vbuf)[256] = (float(*)[256])smem;                 // [16][256] 16KB
    float (*wbuf)[16]  = (float(*)[16])(smem + 16 * 256 * 4); // [48][16]  3KB
    int p0 = bx * 256;
    int og0 = by * 48;
    float acc[48];
#pragma unroll
    for (int i = 0; i < 48; i++) acc[i] = 0.f;

    for (int c0 = 0; c0 < C; c0 += 16) {
        for (int k = tid; k < 16 * 256; k += 256) {           // bulk coalesced stage
            int cc = k >> 8, pp = k & 255;
            vbuf[cc][pp] = v[(size_t)(c0 + cc) * Nv + p0 + pp];
        }
        for (int k = tid; k < 48 * 16; k += 256) {
            int o = k >> 4, cc = k & 15;
            wbuf[o][cc] = Wv[(size_t)(og0 + o) * C + c0 + cc];
        }
        __syncthreads();
#pragma unroll 4
        for (int cc = 0; cc < 16; cc++) {
            float vv = vbuf[cc][tid];                          // conflict-free
#pragma unroll
            for (int o = 0; o < 48; o++)
                acc[o] = fmaf(wbuf[o][cc], vv, acc[o]);        // broadcast
        }
        __syncthreads();
    }

    int p = p0 + tid;
#pragma unroll
    for (int q = 0; q < 2; q++) {
        int h = og0 / 24 + q;
        __half tmp[24];
#pragma unroll
        for (int j = 0; j < 24; j++) tmp[j] = __float2half(acc[q * 24 + j]);
        uint4* dst = (uint4*)(valT + ((size_t)h * Nv + p) * 24);   // 48B offset, 16B aligned
        const uint4* s4 = (const uint4*)tmp;
        dst[0] = s4[0]; dst[1] = s4[1]; dst[2] = s4[2];
    }
}

// ids: [0,512) s1 | [512,576) s2 | [576,584) s3
__global__ __launch_bounds__(256)
void valconv_kernel(const float* __restrict__ Wv1, const float* __restrict__ v1, __half* __restrict__ val1T,
                    const float* __restrict__ Wv2, const float* __restrict__ v2, __half* __restrict__ val2T,
                    const float* __restrict__ Wv3, const float* __restrict__ v3, __half* __restrict__ val3T)
{
    __shared__ __align__(16) char smem[19456];
    int id = blockIdx.x;
    int tid = threadIdx.x;
    if (id < 512) {
        valconv_body<64>(smem, Wv1, v1, val1T, 32768, id & 127, id >> 7, tid);
    } else if (id < 576) {
        int i2 = id - 512;
        valconv_body<128>(smem, Wv2, v2, val2T, 4096, i2 & 15, i2 >> 4, tid);
    } else {
        int i3 = id - 576;
        valconv_body<256>(smem, Wv3, v3, val3T, 512, i3 & 1, i3 >> 1, tid);
    }
}

// offsets + attention weights; rows 0..383 tanh offsets, 384..511 softmaxed aw
__global__ __launch_bounds__(256)
void offaw_kernel(const float* __restrict__ Wcomb, const float* __restrict__ biasc,
                  const float* __restrict__ qf, float* __restrict__ ob)
{
    __shared__ float xs[128 * 64];
    __shared__ float Wl[32 * 128];
    __shared__ float ls[32 * 64];
    int tid = threadIdx.x;
    int n0 = blockIdx.x * 64;
    int og0 = blockIdx.y * 32;
    for (int k = tid; k < 128 * 64; k += 256) xs[k] = qf[(size_t)(k >> 6) * N_Q + n0 + (k & 63)];
    for (int k = tid; k < 32 * 128; k += 256) Wl[k] = Wcomb[(size_t)og0 * 128 + k];
    __syncthreads();

    int wv = tid >> 6, lane = tid & 63;
    float acc[8];
#pragma unroll
    for (int i = 0; i < 8; i++) acc[i] = 0.f;
    for (int c = 0; c < 128; c++) {
        float xv = xs[c * 64 + lane];
#pragma unroll
        for (int i = 0; i < 8; i++)
            acc[i] = fmaf(Wl[(wv * 8 + i) * 128 + c], xv, acc[i]);
    }

    if (og0 < 384) {
#pragma unroll
        for (int i = 0; i < 8; i++) {
            int o = og0 + wv * 8 + i;
            ob[(size_t)o * N_Q + n0 + lane] = tanhf(acc[i] + biasc[o]) * 0.35f;
        }
    } else {
#pragma unroll
        for (int i = 0; i < 8; i++) {
            int o = og0 + wv * 8 + i;
            ls[(wv * 8 + i) * 64 + lane] = acc[i] + biasc[o];
        }
        __syncthreads();
        if (tid < 128) {
            int hl = tid >> 6;
            int n2 = tid & 63;
            float v[16];
            float m = -1e30f;
#pragma unroll
            for (int j = 0; j < 16; j++) { v[j] = ls[(hl * 16 + j) * 64 + n2]; m = fmaxf(m, v[j]); }
            float ssum = 0.f;
#pragma unroll
            for (int j = 0; j < 16; j++) { v[j] = __expf(v[j] - m); ssum += v[j]; }
            float inv = 1.0f / ssum;
            int orow = og0 + hl * 16;
#pragma unroll
            for (int j = 0; j < 16; j++)
                ob[(size_t)(orow + j) * N_Q + n0 + n2] = v[j] * inv;
        }
    }
}

// sampling; id mapping: s0 slab-grouped, s1 pinned id%8==h, s2/3 free
__global__ __launch_bounds__(256)
void sample_kernel(const float* __restrict__ offb, const float* __restrict__ awb,
                   const __half* __restrict__ v0T, const __half* __restrict__ val1T,
                   const __half* __restrict__ val2T, const __half* __restrict__ val3T,
                   const float* __restrict__ Wv0,
                   __half* __restrict__ accb)
{
    int tid = threadIdx.x;
    int id = blockIdx.x;
    int s, h, p, t;
    if (id < 512) {
        s = 0; int r = id & 7; int j = id >> 3;
        t = r + 8 * (j >> 5);
        int rest = j & 31; h = rest >> 2; p = rest & 3;
    } else if (id < 1024) {
        s = 1; int i = id - 512; h = i & 7;
        int j = i >> 3; t = j & 15; p = j >> 4;
    } else {
        int i = id - 1024; s = 2 + (i >> 9);
        int i2 = i & 511; t = i2 & 15; p = (i2 >> 4) & 3; h = i2 >> 6;
    }
    int n = t * 256 + tid;
    int sp = s * 4 + p;

    int wx = n & 15, hy = (n >> 4) & 15, dz = n >> 8;
    const float step = 2.0f / 15.0f;
    float bx = -1.f + wx * step;
    float by = -1.f + hy * step;
    float bz = -1.f + dz * step;

    float acc[HEAD_DIM];
#pragma unroll
    for (int j = 0; j < HEAD_DIM; j++) acc[j] = 0.f;

    int S = 64;
    const __half* srcT = v0T;
    if (s == 1)      { S = 32; srcT = val1T; }
    else if (s == 2) { S = 16; srcT = val2T; }
    else if (s == 3) { S = 8;  srcT = val3T; }
    float fS = (float)S;

    int orow = ((h * 4 + s) * 4 + p) * 3;
    float ox = offb[(orow + 0) * N_Q + n];
    float oy = offb[(orow + 1) * N_Q + n];
    float oz = offb[(orow + 2) * N_Q + n];
    float awv = awb[(h * 16 + s * 4 + p) * N_Q + n];

    float ix = fminf(fmaxf(((bx + ox + 1.f) * fS - 1.f) * 0.5f, 0.f), fS - 1.f);
    float iy = fminf(fmaxf(((by + oy + 1.f) * fS - 1.f) * 0.5f, 0.f), fS - 1.f);
    float iz = fminf(fmaxf(((bz + oz + 1.f) * fS - 1.f) * 0.5f, 0.f), fS - 1.f);

    float x0f = floorf(ix), y0f = floorf(iy), z0f = floorf(iz);
    float fx = ix - x0f, fy = iy - y0f, fz = iz - z0f;
    int x0 = (int)x0f, y0 = (int)y0f, z0 = (int)z0f;
    int x1 = min(x0 + 1, S - 1), y1 = min(y0 + 1, S - 1), z1 = min(z0 + 1, S - 1);

    int r000 = (z0 * S + y0) * S + x0, r001 = (z0 * S + y0) * S + x1;
    int r010 = (z0 * S + y1) * S + x0, r011 = (z0 * S + y1) * S + x1;
    int r100 = (z1 * S + y0) * S + x0, r101 = (z1 * S + y0) * S + x1;
    int r110 = (z1 * S + y1) * S + x0, r111 = (z1 * S + y1) * S + x1;

    float gx1 = fx, gx0 = 1.f - fx;
    float gy1 = fy, gy0 = 1.f - fy;
    float gz1 = fz, gz0 = 1.f - fz;
    float w000 = gz0 * gy0 * gx0 * awv, w001 = gz0 * gy0 * gx1 * awv;
    float w010 = gz0 * gy1 * gx0 * awv, w011 = gz0 * gy1 * gx1 * awv;
    float w100 = gz1 * gy0 * gx0 * awv, w101 = gz1 * gy0 * gx1 * awv;
    float w110 = gz1 * gy1 * gx0 * awv, w111 = gz1 * gy1 * gx1 * awv;

    if (s == 0) {
        const float* Wvh = Wv0 + h * HEAD_DIM * 32;
#pragma unroll
        for (int c8 = 0; c8 < 32; c8 += 8) {
            float u[8] = {0.f, 0.f, 0.f, 0.f, 0.f, 0.f, 0.f, 0.f};
            fma8h(u, w000, srcT + r000 * 32 + c8);
            fma8h(u, w001, srcT + r001 * 32 + c8);
            fma8h(u, w010, srcT + r010 * 32 + c8);
            fma8h(u, w011, srcT + r011 * 32 + c8);
            fma8h(u, w100, srcT + r100 * 32 + c8);
            fma8h(u, w101, srcT + r101 * 32 + c8);
            fma8h(u, w110, srcT + r110 * 32 + c8);
            fma8h(u, w111, srcT + r111 * 32 + c8);
#pragma unroll
            for (int j = 0; j < HEAD_DIM; j++) {
                const float* wp = Wvh + j * 32 + c8;
                float4 wa = ld4(wp), wb = ld4(wp + 4);
                acc[j] = fmaf(wa.x, u[0], fmaf(wa.y, u[1], fmaf(wa.z, u[2], fmaf(wa.w, u[3],
                         fmaf(wb.x, u[4], fmaf(wb.y, u[5], fmaf(wb.z, u[6], fmaf(wb.w, u[7], acc[j]))))))));
            }
        }
    } else {
        int NvS = S * S * S;
        const __half* base = srcT + (size_t)h * NvS * HEAD_DIM;   // head-major
        corner24(acc, w000, base + (size_t)r000 * HEAD_DIM);
        corner24(acc, w001, base + (size_t)r001 * HEAD_DIM);
        corner24(acc, w010, base + (size_t)r010 * HEAD_DIM);
        corner24(acc, w011, base + (size_t)r011 * HEAD_DIM);
        corner24(acc, w100, base + (size_t)r100 * HEAD_DIM);
        corner24(acc, w101, base + (size_t)r101 * HEAD_DIM);
        corner24(acc, w110, base + (size_t)r110 * HEAD_DIM);
        corner24(acc, w111, base + (size_t)r111 * HEAD_DIM);
    }

    __half* ab = accb + (size_t)sp * HIDDEN * N_Q;
#pragma unroll
    for (int j = 0; j < HEAD_DIM; j++) ab[(h * HEAD_DIM + j) * N_Q + n] = __float2half(acc[j]);
}

// accsum (fp16 out) = sum over the 16 (s,p) fp16 slices
__global__ __launch_bounds__(256)
void accsum_kernel(const __half* __restrict__ accb, __half* __restrict__ accsum)
{
    int i = blockIdx.x * 256 + threadIdx.x;
    const int SB8 = HIDDEN * N_Q / 8;
    const uint4* src = (const uint4*)accb;
    float a[8] = {0.f, 0.f, 0.f, 0.f, 0.f, 0.f, 0.f, 0.f};
#pragma unroll
    for (int sp = 0; sp < 16; sp++) {
        uint4 r = src[sp * SB8 + i];
        const __half2* h2 = (const __half2*)&r;
#pragma unroll
        for (int k = 0; k < 4; k++) {
            float2 f = __half22float2(h2[k]);
            a[2 * k] += f.x; a[2 * k + 1] += f.y;
        }
    }
    uint4 o;
    __half2* oh = (__half2*)&o;
#pragma unroll
    for (int k = 0; k < 4; k++)
        oh[k] = __float22half2_rn(make_float2(a[2 * k], a[2 * k + 1]));
    ((uint4*)accsum)[i] = o;
}

// out[o,n] = sum_c Wout[o,c] * accsum[c,n]  (fp16 input)
__global__ __launch_bounds__(256)
void outconv_kernel(const float* __restrict__ Wout, const __half* __restrict__ accsum,
                    float* __restrict__ out)
{
    __shared__ float xs[HIDDEN * 64];
    __shared__ float Wl[64 * HIDDEN];
    int tid = threadIdx.x;
    int n0 = blockIdx.x * 64;
    int og0 = blockIdx.y * 64;
    for (int k = tid; k < HIDDEN * 8; k += 256) {
        int c = k >> 3, seg = k & 7;
        uint4 r = *(const uint4*)(accsum + (size_t)c * N_Q + n0 + seg * 8);
        const __half2* h2 = (const __half2*)&r;
#pragma unroll
        for (int j = 0; j < 4; j++) {
            float2 f = __half22float2(h2[j]);
            xs[c * 64 + seg * 8 + 2 * j]     = f.x;
            xs[c * 64 + seg * 8 + 2 * j + 1] = f.y;
        }
    }
    for (int k = tid; k < 64 * HIDDEN; k += 256) Wl[k] = Wout[(size_t)og0 * HIDDEN + k];
    __syncthreads();

    int wv = tid >> 6, lane = tid & 63;
    float acc[16];
#pragma unroll
    for (int i = 0; i < 16; i++) acc[i] = 0.f;
    for (int c = 0; c < HIDDEN; c++) {
        float xv = xs[c * 64 + lane];
#pragma unroll
        for (int i = 0; i < 16; i++)
            acc[i] = fmaf(Wl[(wv * 16 + i) * HIDDEN + c], xv, acc[i]);
    }
#pragma unroll
    for (int i = 0; i < 16; i++)
        out[(size_t)(og0 + wv * 16 + i) * N_Q + n0 + lane] = acc[i];
}

// InstanceNorm3d per channel (in-place on d_out)
__global__ __launch_bounds__(256)
void inorm_kernel(float* __restrict__ out, const float* __restrict__ gamma,
                  const float* __restrict__ beta)
{
    int o = blockIdx.x;
    int tid = threadIdx.x;
    float s = 0.f, s2 = 0.f;
    for (int n = tid; n < N_Q; n += 256) {
        float v = out[o * N_Q + n];
        s += v; s2 += v * v;
    }
    __shared__ float rs[256], rs2[256];
    rs[tid] = s; rs2[tid] = s2;
    __syncthreads();
    for (int k = 128; k > 0; k >>= 1) {
        if (tid < k) { rs[tid] += rs[tid + k]; rs2[tid] += rs2[tid + k]; }
        __syncthreads();
    }
    float mu = rs[0] * (1.0f / N_Q);
    float var = rs2[0] * (1.0f / N_Q) - mu * mu;
    float rstd = rsqrtf(var + 1e-5f);
    float g = gamma[o] * rstd;
    float b = beta[o] - mu * g;
    for (int n = tid; n < N_Q; n += 256) {
        out[o * N_Q + n] = fmaf(out[o * N_Q + n], g, b);
    }
}

extern "C" void kernel_launch(void* const* d_in, const int* in_sizes, int n_in,
                              void* d_out, int out_size, void* d_ws, size_t ws_size,
                              hipStream_t stream)
{
    const float* qf    = (const float*)d_in[0];
    const float* v0    = (const float*)d_in[1];
    const float* v1    = (const float*)d_in[2];
    const float* v2    = (const float*)d_in[3];
    const float* v3    = (const float*)d_in[4];
    const float* Wq    = (const float*)d_in[5];
    const float* Wv0   = (const float*)d_in[6];
    const float* Wv1   = (const float*)d_in[7];
    const float* Wv2   = (const float*)d_in[8];
    const float* Wv3   = (const float*)d_in[9];
    const float* Woff  = (const float*)d_in[10];
    const float* boff  = (const float*)d_in[11];
    const float* Wwt   = (const float*)d_in[12];
    const float* bwt   = (const float*)d_in[13];
    const float* Wout  = (const float*)d_in[14];
    const float* gamma = (const float*)d_in[15];
    const float* beta  = (const float*)d_in[16];
    float* out = (float*)d_out;

    float* ws     = (float*)d_ws;
    float*  Wcomb  = ws;                                 // 65536 f
    float*  biasc  = Wcomb  + 65536;                     // 512 f
    float*  offb   = biasc  + 512;                       // 512*4096 f (0..383 off, 384..511 aw)
    float*  awb    = offb   + 384 * 4096;
    __half* v0T    = (__half*)(offb + 2097152);          // [262144][32] h
    __half* val1T  = (__half*)((float*)v0T + 4194304);   // [8][32768][24] h (3145728 f)
    __half* val2T  = (__half*)((float*)val1T + 3145728); // [8][4096][24] h (393216 f)
    __half* val3T  = (__half*)((float*)val2T + 393216);  // [8][512][24] h (49152 f)
    __half* accb   = (__half*)((float*)val3T + 49152);   // 16*192*4096 h (6291456 f)
    __half* accsum = accb + 12582912;                    // 192*4096 h (393216 f)

    // low-VGPR prep: v0 transpose + Wq folding
    prep1_kernel<<<1280, 256, 0, stream>>>(v0, v0T, Woff, Wwt, Wq, boff, bwt, Wcomb, biasc);
    // high-VGPR compute-bound value convs (LDS-staged)
    valconv_kernel<<<584, 256, 0, stream>>>(Wv1, v1, val1T, Wv2, v2, val2T, Wv3, v3, val3T);
    // offsets + attention weights (fused softmax)
    offaw_kernel<<<dim3(64, 16), 256, 0, stream>>>(Wcomb, biasc, qf, offb);
    // deformable sampling
    sample_kernel<<<2048, 256, 0, stream>>>(offb, awb, v0T, val1T, val2T, val3T, Wv0, accb);
    // reduce the 16 (s,p) fp16 slices -> fp16
    accsum_kernel<<<384, 256, 0, stream>>>(accb, accsum);
    // final 1x1 conv
    outconv_kernel<<<dim3(64, 2), 256, 0, stream>>>(Wout, accsum, out);
    // instance norm in-place
    inorm_kernel<<<128, 256, 0, stream>>>(out, gamma, beta);
}

// Round 16
// 262.168 us; speedup vs baseline: 1.3729x; 1.3729x over previous
//
#include <hip/hip_runtime.h>
#include <hip/hip_fp16.h>
#include <cmath>

#define N_Q 4096
#define HEADS 8
#define HEAD_DIM 24
#define HIDDEN 192

__device__ __forceinline__ float4 ld4(const float* p) { return *(const float4*)p; }

// accumulate u[0..7] += w * fp16x8 at p (16B aligned)
__device__ __forceinline__ void fma8h(float* u, float w, const __half* p) {
    uint4 raw = *(const uint4*)p;
    const __half2* h2 = reinterpret_cast<const __half2*>(&raw);
#pragma unroll
    for (int k = 0; k < 4; k++) {
        float2 f = __half22float2(h2[k]);
        u[2 * k]     = fmaf(w, f.x, u[2 * k]);
        u[2 * k + 1] = fmaf(w, f.y, u[2 * k + 1]);
    }
}

// acc[0..23] += w * fp16x24 at p (16B-aligned: offsets are 48B multiples)
__device__ __forceinline__ void corner24(float* acc, float w, const __half* p) {
    fma8h(acc,      w, p);
    fma8h(acc + 8,  w, p + 8);
    fma8h(acc + 16, w, p + 16);
}

// ---------------- prep bodies (share one 33792B smem buffer; all low-VGPR) ----------------

// [32, 262144] f32 -> [262144, 32] fp16, 256-pos tile
__device__ __forceinline__ void transpose_body(char* smem, const float* __restrict__ src,
                                               __half* __restrict__ dst, int bx, int tid)
{
    float (*lds)[33] = (float(*)[33])smem;
    const int Nv = 262144;
    int pos0 = bx * 256;
    for (int k = tid; k < 256 * 32; k += 256) {
        int c = k >> 8, p = k & 255;
        lds[p][c] = src[(size_t)c * Nv + pos0 + p];
    }
    __syncthreads();
    for (int k = tid; k < 256 * 32; k += 256) {
        int p = k >> 5, c = k & 31;
        dst[(size_t)(pos0 + p) * 32 + c] = __float2half(lds[p][c]);
    }
}

// valconv, one head per block (24 outputs), 64 positions; weights in LDS,
// read back as float4 (1 ds_read_b128 per 4 c's per output); v loaded direct
// from global (coalesced 64-wide, 4 independent loads in flight); output
// stored DIRECTLY head-major valT[h][pos][24] (3 dwords per thread, no LDS).
template<int C>
__device__ __forceinline__ void valconv24_body(char* smem, const float* __restrict__ Wv,
                                               const float* __restrict__ v,
                                               __half* __restrict__ valT, int Nv,
                                               int bx, int h, int tid)
{
    float* Wl = (float*)smem;                       // 24*C floats (max 24KB at C=256)
    int p0 = bx * 64;
    for (int k = tid; k < 24 * C; k += 256)
        Wl[k] = Wv[(size_t)(h * 24 + k / C) * C + (k % C)];
    __syncthreads();

    int osub = tid >> 6;            // 0..3: outputs osub*6..osub*6+5
    int lane = tid & 63;
    int p = p0 + lane;
    float acc[6];
#pragma unroll
    for (int i = 0; i < 6; i++) acc[i] = 0.f;

    for (int c = 0; c < C; c += 4) {
        float va = v[(size_t)c * Nv + p];
        float vb = v[(size_t)(c + 1) * Nv + p];
        float vc = v[(size_t)(c + 2) * Nv + p];
        float vd = v[(size_t)(c + 3) * Nv + p];
#pragma unroll
        for (int i = 0; i < 6; i++) {
            float4 w4 = *(const float4*)&Wl[(osub * 6 + i) * C + c];
            acc[i] = fmaf(w4.x, va, fmaf(w4.y, vb, fmaf(w4.z, vc, fmaf(w4.w, vd, acc[i]))));
        }
    }

    __half tmp[6];
#pragma unroll
    for (int i = 0; i < 6; i++) tmp[i] = __float2half(acc[i]);
    unsigned int* dst = (unsigned int*)(valT + ((size_t)h * Nv + p) * 24 + osub * 6);
    const unsigned int* s4 = (const unsigned int*)tmp;
    dst[0] = s4[0]; dst[1] = s4[1]; dst[2] = s4[2];
}

// Wcomb (512x128) = concat(Woff,Wwt) @ Wq ; biasc = concat(boff,bwt)
__device__ __forceinline__ void wcomb_body(int bx, int tid,
                                           const float* __restrict__ Woff,
                                           const float* __restrict__ Wwt,
                                           const float* __restrict__ Wq,
                                           const float* __restrict__ boff,
                                           const float* __restrict__ bwt,
                                           float* __restrict__ Wcomb,
                                           float* __restrict__ biasc)
{
    int o = bx * 2 + (tid >> 7);
    int c = tid & 127;
    const float* A = (o < 384) ? (Woff + (size_t)o * 192) : (Wwt + (size_t)(o - 384) * 192);
    float s = 0.f;
#pragma unroll 4
    for (int k = 0; k < 192; k++) s = fmaf(A[k], Wq[k * 128 + c], s);
    Wcomb[(size_t)o * 128 + c] = s;
    if (c == 0) biasc[o] = (o < 384) ? boff[o] : bwt[o - 384];
}

// ids: [0,1024) transpose | [1024,5120) s1 (512 tiles x 8 heads)
//      | [5120,5632) s2 (64x8) | [5632,5696) s3 (8x8) | [5696,5952) wcomb
__global__ __launch_bounds__(256)
void prep_kernel(const float* __restrict__ v0, __half* __restrict__ v0T,
                 const float* __restrict__ Wv1, const float* __restrict__ v1, __half* __restrict__ val1T,
                 const float* __restrict__ Wv2, const float* __restrict__ v2, __half* __restrict__ val2T,
                 const float* __restrict__ Wv3, const float* __restrict__ v3, __half* __restrict__ val3T,
                 const float* __restrict__ Woff, const float* __restrict__ Wwt,
                 const float* __restrict__ Wq, const float* __restrict__ boff,
                 const float* __restrict__ bwt, float* __restrict__ Wcomb,
                 float* __restrict__ biasc)
{
    __shared__ __align__(16) char smem[33792];
    int id = blockIdx.x;
    int tid = threadIdx.x;
    if (id < 1024) {
        transpose_body(smem, v0, v0T, id, tid);
    } else if (id < 5120) {
        int i1 = id - 1024;
        valconv24_body<64>(smem, Wv1, v1, val1T, 32768, i1 & 511, i1 >> 9, tid);
    } else if (id < 5632) {
        int i2 = id - 5120;
        valconv24_body<128>(smem, Wv2, v2, val2T, 4096, i2 & 63, i2 >> 6, tid);
    } else if (id < 5696) {
        int i3 = id - 5632;
        valconv24_body<256>(smem, Wv3, v3, val3T, 512, i3 & 7, i3 >> 3, tid);
    } else {
        wcomb_body(id - 5696, tid, Woff, Wwt, Wq, boff, bwt, Wcomb, biasc);
    }
}

// offsets + attention weights; rows 0..383 tanh offsets, 384..511 softmaxed aw
__global__ __launch_bounds__(256)
void offaw_kernel(const float* __restrict__ Wcomb, const float* __restrict__ biasc,
                  const float* __restrict__ qf, float* __restrict__ ob)
{
    __shared__ float xs[128 * 64];
    __shared__ float Wl[32 * 128];
    __shared__ float ls[32 * 64];
    int tid = threadIdx.x;
    int n0 = blockIdx.x * 64;
    int og0 = blockIdx.y * 32;
    for (int k = tid; k < 128 * 64; k += 256) xs[k] = qf[(size_t)(k >> 6) * N_Q + n0 + (k & 63)];
    for (int k = tid; k < 32 * 128; k += 256) Wl[k] = Wcomb[(size_t)og0 * 128 + k];
    __syncthreads();

    int wv = tid >> 6, lane = tid & 63;
    float acc[8];
#pragma unroll
    for (int i = 0; i < 8; i++) acc[i] = 0.f;
    for (int c = 0; c < 128; c++) {
        float xv = xs[c * 64 + lane];
#pragma unroll
        for (int i = 0; i < 8; i++)
            acc[i] = fmaf(Wl[(wv * 8 + i) * 128 + c], xv, acc[i]);
    }

    if (og0 < 384) {
#pragma unroll
        for (int i = 0; i < 8; i++) {
            int o = og0 + wv * 8 + i;
            ob[(size_t)o * N_Q + n0 + lane] = tanhf(acc[i] + biasc[o]) * 0.35f;
        }
    } else {
#pragma unroll
        for (int i = 0; i < 8; i++) {
            int o = og0 + wv * 8 + i;
            ls[(wv * 8 + i) * 64 + lane] = acc[i] + biasc[o];
        }
        __syncthreads();
        if (tid < 128) {
            int hl = tid >> 6;
            int n2 = tid & 63;
            float v[16];
            float m = -1e30f;
#pragma unroll
            for (int j = 0; j < 16; j++) { v[j] = ls[(hl * 16 + j) * 64 + n2]; m = fmaxf(m, v[j]); }
            float ssum = 0.f;
#pragma unroll
            for (int j = 0; j < 16; j++) { v[j] = __expf(v[j] - m); ssum += v[j]; }
            float inv = 1.0f / ssum;
            int orow = og0 + hl * 16;
#pragma unroll
            for (int j = 0; j < 16; j++)
                ob[(size_t)(orow + j) * N_Q + n0 + n2] = v[j] * inv;
        }
    }
}

// sampling; id mapping: s0 slab-grouped, s1 pinned id%8==h, s2/3 free
__global__ __launch_bounds__(256)
void sample_kernel(const float* __restrict__ offb, const float* __restrict__ awb,
                   const __half* __restrict__ v0T, const __half* __restrict__ val1T,
                   const __half* __restrict__ val2T, const __half* __restrict__ val3T,
                   const float* __restrict__ Wv0,
                   __half* __restrict__ accb)
{
    int tid = threadIdx.x;
    int id = blockIdx.x;
    int s, h, p, t;
    if (id < 512) {
        s = 0; int r = id & 7; int j = id >> 3;
        t = r + 8 * (j >> 5);
        int rest = j & 31; h = rest >> 2; p = rest & 3;
    } else if (id < 1024) {
        s = 1; int i = id - 512; h = i & 7;
        int j = i >> 3; t = j & 15; p = j >> 4;
    } else {
        int i = id - 1024; s = 2 + (i >> 9);
        int i2 = i & 511; t = i2 & 15; p = (i2 >> 4) & 3; h = i2 >> 6;
    }
    int n = t * 256 + tid;
    int sp = s * 4 + p;

    int wx = n & 15, hy = (n >> 4) & 15, dz = n >> 8;
    const float step = 2.0f / 15.0f;
    float bx = -1.f + wx * step;
    float by = -1.f + hy * step;
    float bz = -1.f + dz * step;

    float acc[HEAD_DIM];
#pragma unroll
    for (int j = 0; j < HEAD_DIM; j++) acc[j] = 0.f;

    int S = 64;
    const __half* srcT = v0T;
    if (s == 1)      { S = 32; srcT = val1T; }
    else if (s == 2) { S = 16; srcT = val2T; }
    else if (s == 3) { S = 8;  srcT = val3T; }
    float fS = (float)S;

    int orow = ((h * 4 + s) * 4 + p) * 3;
    float ox = offb[(orow + 0) * N_Q + n];
    float oy = offb[(orow + 1) * N_Q + n];
    float oz = offb[(orow + 2) * N_Q + n];
    float awv = awb[(h * 16 + s * 4 + p) * N_Q + n];

    float ix = fminf(fmaxf(((bx + ox + 1.f) * fS - 1.f) * 0.5f, 0.f), fS - 1.f);
    float iy = fminf(fmaxf(((by + oy + 1.f) * fS - 1.f) * 0.5f, 0.f), fS - 1.f);
    float iz = fminf(fmaxf(((bz + oz + 1.f) * fS - 1.f) * 0.5f, 0.f), fS - 1.f);

    float x0f = floorf(ix), y0f = floorf(iy), z0f = floorf(iz);
    float fx = ix - x0f, fy = iy - y0f, fz = iz - z0f;
    int x0 = (int)x0f, y0 = (int)y0f, z0 = (int)z0f;
    int x1 = min(x0 + 1, S - 1), y1 = min(y0 + 1, S - 1), z1 = min(z0 + 1, S - 1);

    int r000 = (z0 * S + y0) * S + x0, r001 = (z0 * S + y0) * S + x1;
    int r010 = (z0 * S + y1) * S + x0, r011 = (z0 * S + y1) * S + x1;
    int r100 = (z1 * S + y0) * S + x0, r101 = (z1 * S + y0) * S + x1;
    int r110 = (z1 * S + y1) * S + x0, r111 = (z1 * S + y1) * S + x1;

    float gx1 = fx, gx0 = 1.f - fx;
    float gy1 = fy, gy0 = 1.f - fy;
    float gz1 = fz, gz0 = 1.f - fz;
    float w000 = gz0 * gy0 * gx0 * awv, w001 = gz0 * gy0 * gx1 * awv;
    float w010 = gz0 * gy1 * gx0 * awv, w011 = gz0 * gy1 * gx1 * awv;
    float w100 = gz1 * gy0 * gx0 * awv, w101 = gz1 * gy0 * gx1 * awv;
    float w110 = gz1 * gy1 * gx0 * awv, w111 = gz1 * gy1 * gx1 * awv;

    if (s == 0) {
        const float* Wvh = Wv0 + h * HEAD_DIM * 32;
#pragma unroll
        for (int c8 = 0; c8 < 32; c8 += 8) {
            float u[8] = {0.f, 0.f, 0.f, 0.f, 0.f, 0.f, 0.f, 0.f};
            fma8h(u, w000, srcT + r000 * 32 + c8);
            fma8h(u, w001, srcT + r001 * 32 + c8);
            fma8h(u, w010, srcT + r010 * 32 + c8);
            fma8h(u, w011, srcT + r011 * 32 + c8);
            fma8h(u, w100, srcT + r100 * 32 + c8);
            fma8h(u, w101, srcT + r101 * 32 + c8);
            fma8h(u, w110, srcT + r110 * 32 + c8);
            fma8h(u, w111, srcT + r111 * 32 + c8);
#pragma unroll
            for (int j = 0; j < HEAD_DIM; j++) {
                const float* wp = Wvh + j * 32 + c8;
                float4 wa = ld4(wp), wb = ld4(wp + 4);
                acc[j] = fmaf(wa.x, u[0], fmaf(wa.y, u[1], fmaf(wa.z, u[2], fmaf(wa.w, u[3],
                         fmaf(wb.x, u[4], fmaf(wb.y, u[5], fmaf(wb.z, u[6], fmaf(wb.w, u[7], acc[j]))))))));
            }
        }
    } else {
        int NvS = S * S * S;
        const __half* base = srcT + (size_t)h * NvS * HEAD_DIM;   // head-major
        corner24(acc, w000, base + (size_t)r000 * HEAD_DIM);
        corner24(acc, w001, base + (size_t)r001 * HEAD_DIM);
        corner24(acc, w010, base + (size_t)r010 * HEAD_DIM);
        corner24(acc, w011, base + (size_t)r011 * HEAD_DIM);
        corner24(acc, w100, base + (size_t)r100 * HEAD_DIM);
        corner24(acc, w101, base + (size_t)r101 * HEAD_DIM);
        corner24(acc, w110, base + (size_t)r110 * HEAD_DIM);
        corner24(acc, w111, base + (size_t)r111 * HEAD_DIM);
    }

    __half* ab = accb + (size_t)sp * HIDDEN * N_Q;
#pragma unroll
    for (int j = 0; j < HEAD_DIM; j++) ab[(h * HEAD_DIM + j) * N_Q + n] = __float2half(acc[j]);
}

// accsum (fp16 out) = sum over the 16 (s,p) fp16 slices
__global__ __launch_bounds__(256)
void accsum_kernel(const __half* __restrict__ accb, __half* __restrict__ accsum)
{
    int i = blockIdx.x * 256 + threadIdx.x;
    const int SB8 = HIDDEN * N_Q / 8;
    const uint4* src = (const uint4*)accb;
    float a[8] = {0.f, 0.f, 0.f, 0.f, 0.f, 0.f, 0.f, 0.f};
#pragma unroll
    for (int sp = 0; sp < 16; sp++) {
        uint4 r = src[sp * SB8 + i];
        const __half2* h2 = (const __half2*)&r;
#pragma unroll
        for (int k = 0; k < 4; k++) {
            float2 f = __half22float2(h2[k]);
            a[2 * k] += f.x; a[2 * k + 1] += f.y;
        }
    }
    uint4 o;
    __half2* oh = (__half2*)&o;
#pragma unroll
    for (int k = 0; k < 4; k++)
        oh[k] = __float22half2_rn(make_float2(a[2 * k], a[2 * k + 1]));
    ((uint4*)accsum)[i] = o;
}

// out[o,n] = sum_c Wout[o,c] * accsum[c,n]  (fp16 input)
__global__ __launch_bounds__(256)
void outconv_kernel(const float* __restrict__ Wout, const __half* __restrict__ accsum,
                    float* __restrict__ out)
{
    __shared__ float xs[HIDDEN * 64];
    __shared__ float Wl[64 * HIDDEN];
    int tid = threadIdx.x;
    int n0 = blockIdx.x * 64;
    int og0 = blockIdx.y * 64;
    for (int k = tid; k < HIDDEN * 8; k += 256) {
        int c = k >> 3, seg = k & 7;
        uint4 r = *(const uint4*)(accsum + (size_t)c * N_Q + n0 + seg * 8);
        const __half2* h2 = (const __half2*)&r;
#pragma unroll
        for (int j = 0; j < 4; j++) {
            float2 f = __half22float2(h2[j]);
            xs[c * 64 + seg * 8 + 2 * j]     = f.x;
            xs[c * 64 + seg * 8 + 2 * j + 1] = f.y;
        }
    }
    for (int k = tid; k < 64 * HIDDEN; k += 256) Wl[k] = Wout[(size_t)og0 * HIDDEN + k];
    __syncthreads();

    int wv = tid >> 6, lane = tid & 63;
    float acc[16];
#pragma unroll
    for (int i = 0; i < 16; i++) acc[i] = 0.f;
    for (int c = 0; c < HIDDEN; c++) {
        float xv = xs[c * 64 + lane];
#pragma unroll
        for (int i = 0; i < 16; i++)
            acc[i] = fmaf(Wl[(wv * 16 + i) * HIDDEN + c], xv, acc[i]);
    }
#pragma unroll
    for (int i = 0; i < 16; i++)
        out[(size_t)(og0 + wv * 16 + i) * N_Q + n0 + lane] = acc[i];
}

// InstanceNorm3d per channel (in-place on d_out)
__global__ __launch_bounds__(256)
void inorm_kernel(float* __restrict__ out, const float* __restrict__ gamma,
                  const float* __restrict__ beta)
{
    int o = blockIdx.x;
    int tid = threadIdx.x;
    float s = 0.f, s2 = 0.f;
    for (int n = tid; n < N_Q; n += 256) {
        float v = out[o * N_Q + n];
        s += v; s2 += v * v;
    }
    __shared__ float rs[256], rs2[256];
    rs[tid] = s; rs2[tid] = s2;
    __syncthreads();
    for (int k = 128; k > 0; k >>= 1) {
        if (tid < k) { rs[tid] += rs[tid + k]; rs2[tid] += rs2[tid + k]; }
        __syncthreads();
    }
    float mu = rs[0] * (1.0f / N_Q);
    float var = rs2[0] * (1.0f / N_Q) - mu * mu;
    float rstd = rsqrtf(var + 1e-5f);
    float g = gamma[o] * rstd;
    float b = beta[o] - mu * g;
    for (int n = tid; n < N_Q; n += 256) {
        out[o * N_Q + n] = fmaf(out[o * N_Q + n], g, b);
    }
}

extern "C" void kernel_launch(void* const* d_in, const int* in_sizes, int n_in,
                              void* d_out, int out_size, void* d_ws, size_t ws_size,
                              hipStream_t stream)
{
    const float* qf    = (const float*)d_in[0];
    const float* v0    = (const float*)d_in[1];
    const float* v1    = (const float*)d_in[2];
    const float* v2    = (const float*)d_in[3];
    const float* v3    = (const float*)d_in[4];
    const float* Wq    = (const float*)d_in[5];
    const float* Wv0   = (const float*)d_in[6];
    const float* Wv1   = (const float*)d_in[7];
    const float* Wv2   = (const float*)d_in[8];
    const float* Wv3   = (const float*)d_in[9];
    const float* Woff  = (const float*)d_in[10];
    const float* boff  = (const float*)d_in[11];
    const float* Wwt   = (const float*)d_in[12];
    const float* bwt   = (const float*)d_in[13];
    const float* Wout  = (const float*)d_in[14];
    const float* gamma = (const float*)d_in[15];
    const float* beta  = (const float*)d_in[16];
    float* out = (float*)d_out;

    float* ws     = (float*)d_ws;
    float*  Wcomb  = ws;                                 // 65536 f
    float*  biasc  = Wcomb  + 65536;                     // 512 f
    float*  offb   = biasc  + 512;                       // 512*4096 f (0..383 off, 384..511 aw)
    float*  awb    = offb   + 384 * 4096;
    __half* v0T    = (__half*)(offb + 2097152);          // [262144][32] h
    __half* val1T  = (__half*)((float*)v0T + 4194304);   // [8][32768][24] h (3145728 f)
    __half* val2T  = (__half*)((float*)val1T + 3145728); // [8][4096][24] h (393216 f)
    __half* val3T  = (__half*)((float*)val2T + 393216);  // [8][512][24] h (49152 f)
    __half* accb   = (__half*)((float*)val3T + 49152);   // 16*192*4096 h (6291456 f)
    __half* accsum = accb + 12582912;                    // 192*4096 h (393216 f)

    // all independent prep in one low-VGPR launch (r10 structure, improved valconv)
    prep_kernel<<<5952, 256, 0, stream>>>(v0, v0T, Wv1, v1, val1T, Wv2, v2, val2T,
                                          Wv3, v3, val3T, Woff, Wwt, Wq, boff, bwt,
                                          Wcomb, biasc);
    // offsets + attention weights (fused softmax)
    offaw_kernel<<<dim3(64, 16), 256, 0, stream>>>(Wcomb, biasc, qf, offb);
    // deformable sampling
    sample_kernel<<<2048, 256, 0, stream>>>(offb, awb, v0T, val1T, val2T, val3T, Wv0, accb);
    // reduce the 16 (s,p) fp16 slices -> fp16
    accsum_kernel<<<384, 256, 0, stream>>>(accb, accsum);
    // final 1x1 conv
    outconv_kernel<<<dim3(64, 2), 256, 0, stream>>>(Wout, accsum, out);
    // instance norm in-place
    inorm_kernel<<<128, 256, 0, stream>>>(out, gamma, beta);
}